// Round 20
// baseline (126.254 us; speedup 1.0000x reference)
//
#include <hip/hip_runtime.h>
#include <hip/hip_bf16.h>
#include <stdint.h>

#define NN 4096
#define NBLK 260                   // sum_{d=0}^{15} (16-d)*ceil((d+1)/4)

typedef __attribute__((ext_vector_type(8))) __bf16 bf16x8;
typedef __attribute__((ext_vector_type(8))) short  s16x8;
typedef __attribute__((ext_vector_type(4))) float  f32x4;

__device__ __forceinline__ ushort f2bf(float f) {
    uint32_t u = __builtin_bit_cast(uint32_t, f);
    u += 0x7fffu + ((u >> 16) & 1u);            // RNE to bf16
    return (ushort)(u >> 16);
}

// ---------- fused prep: z=0 conv A (triu, bf16), z=1 conv B^T (triu, bf16), z=2 zero C tiles ----------
__global__ __launch_bounds__(256) void prep(const float* __restrict__ A,
                                            const float* __restrict__ B,
                                            ushort* __restrict__ Au,
                                            ushort* __restrict__ BTu,
                                            float* __restrict__ C) {
    const int role = blockIdx.z;
    const int tr = blockIdx.y;
    const int tc = blockIdx.x;
    const int tid = threadIdx.x;

    if (role == 0) {
        if (tc < tr) return;                     // lower A-tiles never read
        const bool diag = (tc == tr);
#pragma unroll
        for (int q = 0; q < 8; ++q) {
            int g = q * 256 + tid;
            int r = g >> 4, c0 = (g & 15) << 3;
            int row = tr * 128 + r, col0 = tc * 128 + c0;
            const float* p = A + (size_t)row * NN + col0;
            f32x4 a0 = *reinterpret_cast<const f32x4*>(p);
            f32x4 a1 = *reinterpret_cast<const f32x4*>(p + 4);
            s16x8 o;
#pragma unroll
            for (int j = 0; j < 8; ++j) {
                float f = (j < 4) ? a0[j] : a1[j - 4];
                if (diag && (col0 + j) < row) f = 0.0f;
                o[j] = (short)f2bf(f);
            }
            *reinterpret_cast<s16x8*>(Au + (size_t)row * NN + col0) = o;
        }
        return;
    }

    if (role == 1) {
        // BTu[j][k] = (j >= k) ? bf16(B[k][j]) : 0 ; tr = k-tile, tc = j-tile
        if (tc < tr) return;
        const bool diag = (tc == tr);
        __shared__ ushort tile[128][129];        // pad 129: transpose read 2-way (free)
#pragma unroll
        for (int q = 0; q < 16; ++q) {
            int g = q * 256 + tid;
            int r = g >> 5, f4 = g & 31;
            int krow = tr * 128 + r;
            const float* p = B + (size_t)krow * NN + tc * 128 + f4 * 4;
            f32x4 v = *reinterpret_cast<const f32x4*>(p);
#pragma unroll
            for (int j = 0; j < 4; ++j) {
                int col = f4 * 4 + j;
                float f = v[j];
                if (diag && (tc * 128 + col) < krow) f = 0.0f;
                tile[r][col] = f2bf(f);
            }
        }
        __syncthreads();
#pragma unroll
        for (int q = 0; q < 8; ++q) {
            int g = q * 256 + tid;
            int orow = g >> 4, ch = g & 15;
            s16x8 o;
#pragma unroll
            for (int j = 0; j < 8; ++j) o[j] = (short)tile[ch * 8 + j][orow];
            *reinterpret_cast<s16x8*>(BTu + (size_t)(tc * 128 + orow) * NN + tr * 128 + ch * 8) = o;
        }
        return;
    }

    // role 2 (128-grid): zero if lower 256-tile OR upper 256-tile with d256 >= 4 (atomic-accumulated)
    {
        int I = tr >> 1, J = tc >> 1;
        bool need = (I > J) || ((J - I) >= 4);
        if (!need) return;
        int r = tid >> 1, cb = (tid & 1) * 64;
        float* p = C + (size_t)(tr * 128 + r) * NN + tc * 128 + cb;
        f32x4 z = {0.f, 0.f, 0.f, 0.f};
#pragma unroll
        for (int v = 0; v < 16; ++v) *reinterpret_cast<f32x4*>(p + v * 4) = z;
    }
}

// ---------------- 256x256-tile split-K MFMA kernel: 8 waves, BK=32, r16 counted-vmcnt pipeline ----------------
// r20: scale r16's verified loop to 256² / 8 waves (catalog m194-m201: this shape fixes the
// small-scale plateau — 32 MFMA : 12 ds_read per wave-step vs 16:8, 2 waves/SIMD in one barrier
// domain). 260 jobs (~1/CU), d-descending (LPT). Per-thread staging = 4 gloads/stage -> vmcnt
// logic identical to r16. acc[8][4] (~200 VGPR) -> 1 block/CU; LDS 64KB.
__global__ __launch_bounds__(512) void trimm_256(const ushort* __restrict__ Au,
                                                 const ushort* __restrict__ BTu,
                                                 float* __restrict__ C) {
    const int tid = threadIdx.x;

    // ---- decode id -> (I, J, chunk c of nch), d descending (longest jobs first) ----
    int id = blockIdx.x;
    int dd = 15, nch = 1, I = 0, c = 0;
    for (dd = 15; dd >= 0; --dd) {
        int nc = (dd + 4) >> 2;                  // ceil((dd+1)/4)
        int cnt = (16 - dd) * nc;
        if (id < cnt) { I = id / nc; c = id % nc; nch = nc; break; }
        id -= cnt;
    }
    const int J = I + dd;
    const int L = dd + 1;                        // k-tiles of 256 in [I, J]
    const int kt0 = (c * L) / nch, kt1 = ((c + 1) * L) / nch;
    const int k_base = (I + kt0) * 256;
    const int nsteps = (kt1 - kt0) * 8;          // BK=32 steps (8..32)

    __shared__ ushort lA[2][256 * 32];           // 2 x 16 KB
    __shared__ ushort lB[2][256 * 32];           // 2 x 16 KB

    const int wid = tid >> 6, lane = tid & 63;
    const int wr = wid >> 2, wc = wid & 3;       // 2 x 4 wave grid; wave out = 128x64
    const int l16 = lane & 15, kh = lane >> 4;

    // staging: 1024 chunks per operand per step; chunk g -> LDS 16B-slot g;
    // source = (row = g>>2, kslot = (g&3)^((g>>3)&3))  [coalescing-preserving XOR swizzle, r16]
    const int g0 = wid * 64 + lane;              // q=0 chunk (0..511)
    const int g1 = 512 + wid * 64 + lane;        // q=1 chunk (512..1023)
    const int ks0 = ((g0 & 3) ^ ((g0 >> 3) & 3)) << 3;
    const int ks1 = ((g1 & 3) ^ ((g1 >> 3) & 3)) << 3;
    const ushort* gaB0 = Au  + (size_t)(I * 256 + (g0 >> 2)) * NN + ks0 + k_base;
    const ushort* gaB1 = Au  + (size_t)(I * 256 + (g1 >> 2)) * NN + ks1 + k_base;
    const ushort* gbB0 = BTu + (size_t)(J * 256 + (g0 >> 2)) * NN + ks0 + k_base;
    const ushort* gbB1 = BTu + (size_t)(J * 256 + (g1 >> 2)) * NN + ks1 + k_base;
    const int lo0 = g0 * 8;                      // ushort offsets
    const int lo1 = g1 * 8;

#define STAGE(buf, off)                                                                            \
    do {                                                                                           \
        __builtin_amdgcn_global_load_lds((const __attribute__((address_space(1))) void*)(gaB0 + (off)), \
                                         (__attribute__((address_space(3))) void*)(&lA[buf][lo0]), 16, 0, 0); \
        __builtin_amdgcn_global_load_lds((const __attribute__((address_space(1))) void*)(gaB1 + (off)), \
                                         (__attribute__((address_space(3))) void*)(&lA[buf][lo1]), 16, 0, 0); \
        __builtin_amdgcn_global_load_lds((const __attribute__((address_space(1))) void*)(gbB0 + (off)), \
                                         (__attribute__((address_space(3))) void*)(&lB[buf][lo0]), 16, 0, 0); \
        __builtin_amdgcn_global_load_lds((const __attribute__((address_space(1))) void*)(gbB1 + (off)), \
                                         (__attribute__((address_space(3))) void*)(&lB[buf][lo1]), 16, 0, 0); \
    } while (0)

    f32x4 zerov = {0.f, 0.f, 0.f, 0.f};
    f32x4 acc[8][4];
#pragma unroll
    for (int m = 0; m < 8; ++m)
#pragma unroll
        for (int n = 0; n < 4; ++n) acc[m][n] = zerov;

    // prologue: 2 stages in flight
    STAGE(0, 0);
    STAGE(1, 32);

    for (int t = 0; t < nsteps; ++t) {
        const int cur = t & 1;
        // wait for stage t only: stage t+1's 4 loads stay outstanding (counted vmcnt, never 0 in-loop)
        if (t + 1 < nsteps) asm volatile("s_waitcnt vmcnt(4)" ::: "memory");
        else                asm volatile("s_waitcnt vmcnt(0)" ::: "memory");
        __builtin_amdgcn_s_barrier();
        __builtin_amdgcn_sched_barrier(0);   // pin ds_reads below the barrier (cross-wave staging)

        bf16x8 af[8], bfr[4];
#pragma unroll
        for (int m = 0; m < 8; ++m) {
            int row = wr * 128 + m * 16 + l16;
            af[m] = *reinterpret_cast<const bf16x8*>(&lA[cur][row * 32 + ((kh ^ ((row >> 1) & 3)) << 3)]);
        }
#pragma unroll
        for (int n = 0; n < 4; ++n) {
            int row = wc * 64 + n * 16 + l16;
            bfr[n] = *reinterpret_cast<const bf16x8*>(&lB[cur][row * 32 + ((kh ^ ((row >> 1) & 3)) << 3)]);
        }

#pragma unroll
        for (int m = 0; m < 8; ++m)
#pragma unroll
            for (int n = 0; n < 4; ++n)
                acc[m][n] = __builtin_amdgcn_mfma_f32_16x16x32_bf16(af[m], bfr[n], acc[m][n], 0, 0, 0);

        __builtin_amdgcn_s_barrier();        // all waves done reading buf[cur]
        __builtin_amdgcn_sched_barrier(0);   // pin the overwrite below the barrier
        if (t + 2 < nsteps) STAGE(cur, (t + 2) * 32);
    }
#undef STAGE

    // C/D layout: col = lane&15, row = (lane>>4)*4 + reg
    const int rowb = I * 256 + wr * 128 + kh * 4;
    const int colb = J * 256 + wc * 64 + l16;
    if (nch == 1) {
#pragma unroll
        for (int m = 0; m < 8; ++m)
#pragma unroll
            for (int n = 0; n < 4; ++n)
#pragma unroll
                for (int r = 0; r < 4; ++r)
                    C[(size_t)(rowb + m * 16 + r) * NN + colb + n * 16] = acc[m][n][r];
    } else {
#pragma unroll
        for (int m = 0; m < 8; ++m)
#pragma unroll
            for (int n = 0; n < 4; ++n)
#pragma unroll
                for (int r = 0; r < 4; ++r)
                    unsafeAtomicAdd(&C[(size_t)(rowb + m * 16 + r) * NN + colb + n * 16], acc[m][n][r]);
    }
}

// ---------------- fp32 fallback (only if ws too small) ----------------
__global__ __launch_bounds__(256) void tri_fp32(const float* __restrict__ A,
                                                const float* __restrict__ B,
                                                float* __restrict__ C) {
    const int bi = blockIdx.y, bj = blockIdx.x, tid = threadIdx.x;
    const int r0 = (tid >> 4) << 2, c0 = (tid & 15) << 2;
    f32x4 z = {0.f, 0.f, 0.f, 0.f};
    if (bi > bj) {
#pragma unroll
        for (int r = 0; r < 4; ++r)
            *reinterpret_cast<f32x4*>(C + (size_t)(bi * 64 + r0 + r) * NN + bj * 64 + c0) = z;
        return;
    }
    __shared__ float As[64][65], Bs[64][65];
    float acc[4][4] = {};
    for (int kt = bi; kt <= bj; ++kt) {
        const int k0 = kt * 64;
#pragma unroll
        for (int q = 0; q < 4; ++q) {
            int g = q * 256 + tid, r = g >> 4, f4 = g & 15;
            f32x4 va = *reinterpret_cast<const f32x4*>(A + (size_t)(bi * 64 + r) * NN + k0 + f4 * 4);
            f32x4 vb = *reinterpret_cast<const f32x4*>(B + (size_t)(k0 + r) * NN + bj * 64 + f4 * 4);
#pragma unroll
            for (int j = 0; j < 4; ++j) {
                As[r][f4 * 4 + j] = (k0 + f4 * 4 + j >= bi * 64 + r) ? va[j] : 0.f;
                Bs[r][f4 * 4 + j] = (bj * 64 + f4 * 4 + j >= k0 + r) ? vb[j] : 0.f;
            }
        }
        __syncthreads();
        for (int kk = 0; kk < 64; ++kk) {
#pragma unroll
            for (int r = 0; r < 4; ++r) {
                float a = As[r0 + r][kk];
#pragma unroll
                for (int cc = 0; cc < 4; ++cc) acc[r][cc] += a * Bs[kk][c0 + cc];
            }
        }
        __syncthreads();
    }
#pragma unroll
    for (int r = 0; r < 4; ++r) {
        f32x4 o = {acc[r][0], acc[r][1], acc[r][2], acc[r][3]};
        *reinterpret_cast<f32x4*>(C + (size_t)(bi * 64 + r0 + r) * NN + bj * 64 + c0) = o;
    }
}

extern "C" void kernel_launch(void* const* d_in, const int* in_sizes, int n_in,
                              void* d_out, int out_size, void* d_ws, size_t ws_size,
                              hipStream_t stream) {
    const float* A = (const float*)d_in[0];
    const float* B = (const float*)d_in[1];
    float* C = (float*)d_out;

    const size_t need = (size_t)2 * NN * NN * sizeof(ushort);   // 64 MB
    if (ws_size >= need) {
        ushort* Au  = (ushort*)d_ws;
        ushort* BTu = Au + (size_t)NN * NN;
        prep<<<dim3(32, 32, 3), 256, 0, stream>>>(A, B, Au, BTu, C);
        trimm_256<<<NBLK, 512, 0, stream>>>(Au, BTu, C);
    } else {
        tri_fp32<<<dim3(64, 64), 256, 0, stream>>>(A, B, C);
    }
}